// Round 1
// baseline (1228.425 us; speedup 1.0000x reference)
//
#include <hip/hip_runtime.h>
#include <hip/hip_bf16.h>

// Problem constants (from reference)
#define NN 50000
#define EE 100000
#define GG 2048
// D = 32 hidden, F_NODE = 11, F_EDGE = 4

// feat = relu(x @ lin0_w.T + lin0_b); thread per (node, out-dim)
__global__ void k_init(const float* __restrict__ x, const float* __restrict__ w,
                       const float* __restrict__ b, float* __restrict__ feat) {
    int idx = blockIdx.x * blockDim.x + threadIdx.x;
    if (idx >= NN * 32) return;
    int n = idx >> 5, o = idx & 31;
    const float* xr = x + n * 11;
    const float* wr = w + o * 11;
    float acc = b[o];
#pragma unroll
    for (int i = 0; i < 11; ++i) acc += xr[i] * wr[i];
    feat[idx] = fmaxf(acc, 0.f);
}

// Per-node message table:
//   y[n, f*32+o] = sum_i feat[n,i] * nn_w[(i*32+o)*4 + f]   (f = 0..3)
//   y[n, 128+o]  = sum_i feat[n,i] * nn_b[i*32+o]           (bias part)
__global__ void k_y(const float* __restrict__ feat, const float* __restrict__ nnw,
                    const float* __restrict__ nnb, float* __restrict__ y) {
    int idx = blockIdx.x * blockDim.x + threadIdx.x;
    if (idx >= NN * 160) return;
    int n = idx / 160;
    int c = idx - n * 160;
    int f = c >> 5, o = c & 31;
    const float* fr = feat + n * 32;
    const float* wp;
    int stride;
    if (f < 4) { wp = nnw + o * 4 + f; stride = 128; }
    else       { wp = nnb + o;         stride = 32;  }
    float acc = 0.f;
#pragma unroll
    for (int i = 0; i < 32; ++i) acc += fr[i] * wp[i * stride];
    y[idx] = acc;
}

// Edge pass: msg[e,o] = y_b[src,o] + sum_f ea[e,f]*y_f[src,o]; scatter-add to aggr[dst]
__global__ void k_edge(const float* __restrict__ y, const float* __restrict__ ea,
                       const int* __restrict__ ei, float* __restrict__ aggr) {
    int idx = blockIdx.x * blockDim.x + threadIdx.x;
    if (idx >= EE * 32) return;
    int e = idx >> 5, o = idx & 31;
    int s = ei[e];
    int d = ei[EE + e];
    const float* yr = y + (long)s * 160;
    float a0 = ea[e * 4 + 0], a1 = ea[e * 4 + 1], a2 = ea[e * 4 + 2], a3 = ea[e * 4 + 3];
    float msg = yr[128 + o] + a0 * yr[o] + a1 * yr[32 + o] + a2 * yr[64 + o] + a3 * yr[96 + o];
    atomicAdd(aggr + (long)d * 32 + o, msg);
}

// Node update: m = relu(aggr + feat@root_w + conv_b); feat = GRU(m, feat)
// 8 nodes per 256-thread block; LDS for feat row and m row (broadcast reads, conflict-free)
__global__ __launch_bounds__(256) void k_update(
    const float* __restrict__ aggr, const float* __restrict__ rootw,
    const float* __restrict__ convb, const float* __restrict__ wi,
    const float* __restrict__ wh, const float* __restrict__ bi,
    const float* __restrict__ bh, float* __restrict__ feat) {
    __shared__ float fs[8][32];
    __shared__ float ms[8][32];
    int t = threadIdx.x;
    int l = t >> 5, o = t & 31;
    int n = blockIdx.x * 8 + l;
    bool valid = (n < NN);
    float f = valid ? feat[n * 32 + o] : 0.f;
    fs[l][o] = f;
    __syncthreads();
    float acc = 0.f;
    if (valid) {
        acc = aggr[n * 32 + o] + convb[o];
#pragma unroll
        for (int i = 0; i < 32; ++i) acc += fs[l][i] * rootw[i * 32 + o];
    }
    float m = fmaxf(acc, 0.f);
    ms[l][o] = m;
    __syncthreads();
    if (!valid) return;
    float gir = bi[o], giz = bi[32 + o], gin = bi[64 + o];
    float ghr = bh[o], ghz = bh[32 + o], ghn = bh[64 + o];
#pragma unroll
    for (int k = 0; k < 32; ++k) {
        float mk = ms[l][k], hk = fs[l][k];
        gir += mk * wi[o * 32 + k];
        giz += mk * wi[(32 + o) * 32 + k];
        gin += mk * wi[(64 + o) * 32 + k];
        ghr += hk * wh[o * 32 + k];
        ghz += hk * wh[(32 + o) * 32 + k];
        ghn += hk * wh[(64 + o) * 32 + k];
    }
    float r = 1.f / (1.f + __expf(-(gir + ghr)));
    float z = 1.f / (1.f + __expf(-(giz + ghz)));
    float nt = tanhf(gin + r * ghn);
    feat[n * 32 + o] = (1.f - z) * nt + z * f;
}

// Mean-pool per graph via atomics (batch is sorted but treated generically)
__global__ void k_pool(const float* __restrict__ feat, const int* __restrict__ batch,
                       float* __restrict__ pooled, float* __restrict__ cnt) {
    int idx = blockIdx.x * blockDim.x + threadIdx.x;
    if (idx >= NN * 32) return;
    int n = idx >> 5, o = idx & 31;
    int g = batch[n];
    atomicAdd(pooled + (long)g * 32 + o, feat[idx]);
    if (o == 0) atomicAdd(cnt + g, 1.f);
}

// logits = (pooled/cnt) @ lin1_w.T + lin1_b; log_softmax over 2 classes
__global__ void k_final(const float* __restrict__ pooled, const float* __restrict__ cnt,
                        const float* __restrict__ w, const float* __restrict__ b,
                        float* __restrict__ out) {
    int g = blockIdx.x * blockDim.x + threadIdx.x;
    if (g >= GG) return;
    float inv = 1.f / fmaxf(cnt[g], 1.f);
    float l0 = b[0], l1 = b[1];
    const float* pr = pooled + g * 32;
#pragma unroll
    for (int k = 0; k < 32; ++k) {
        float p = pr[k] * inv;
        l0 += p * w[k];
        l1 += p * w[32 + k];
    }
    float mx = fmaxf(l0, l1);
    float lse = mx + logf(__expf(l0 - mx) + __expf(l1 - mx));
    out[g * 2 + 0] = l0 - lse;
    out[g * 2 + 1] = l1 - lse;
}

extern "C" void kernel_launch(void* const* d_in, const int* in_sizes, int n_in,
                              void* d_out, int out_size, void* d_ws, size_t ws_size,
                              hipStream_t stream) {
    const float* x        = (const float*)d_in[0];
    const float* edge_attr= (const float*)d_in[1];
    const float* lin0_w   = (const float*)d_in[2];
    const float* lin0_b   = (const float*)d_in[3];
    const float* nn_w     = (const float*)d_in[4];
    const float* nn_b     = (const float*)d_in[5];
    const float* root_w   = (const float*)d_in[6];
    const float* conv_b   = (const float*)d_in[7];
    const float* gru_wi   = (const float*)d_in[8];
    const float* gru_wh   = (const float*)d_in[9];
    const float* gru_bi   = (const float*)d_in[10];
    const float* gru_bh   = (const float*)d_in[11];
    const float* lin1_w   = (const float*)d_in[12];
    const float* lin1_b   = (const float*)d_in[13];
    const int*   edge_idx = (const int*)d_in[14];
    const int*   batch    = (const int*)d_in[15];
    float* out = (float*)d_out;

    float* ws     = (float*)d_ws;
    float* feat   = ws;                       // N*32   = 1,600,000 f
    float* y      = feat + (long)NN * 32;     // N*160  = 8,000,000 f
    float* aggr   = y + (long)NN * 160;       // N*32   = 1,600,000 f
    float* pooled = aggr + (long)NN * 32;     // G*32   =    65,536 f
    float* cnt    = pooled + (long)GG * 32;   // G      =     2,048 f
    // total ~45.1 MB

    hipMemsetAsync(pooled, 0, ((long)GG * 32 + GG) * sizeof(float), stream);

    k_init<<<(NN * 32 + 255) / 256, 256, 0, stream>>>(x, lin0_w, lin0_b, feat);

    for (int it = 0; it < 3; ++it) {
        k_y<<<(NN * 160 + 255) / 256, 256, 0, stream>>>(feat, nn_w, nn_b, y);
        hipMemsetAsync(aggr, 0, (long)NN * 32 * sizeof(float), stream);
        k_edge<<<(EE * 32 + 255) / 256, 256, 0, stream>>>(y, edge_attr, edge_idx, aggr);
        k_update<<<(NN + 7) / 8, 256, 0, stream>>>(aggr, root_w, conv_b, gru_wi, gru_wh,
                                                   gru_bi, gru_bh, feat);
    }

    k_pool<<<(NN * 32 + 255) / 256, 256, 0, stream>>>(feat, batch, pooled, cnt);
    k_final<<<(GG + 255) / 256, 256, 0, stream>>>(pooled, cnt, lin1_w, lin1_b, out);
}

// Round 2
// 818.059 us; speedup vs baseline: 1.5016x; 1.5016x over previous
//
#include <hip/hip_runtime.h>
#include <hip/hip_bf16.h>

// Problem constants (from reference)
#define NN 50000
#define EE 100000
#define GG 2048
// D = 32 hidden, F_NODE = 11, F_EDGE = 4

// feat = relu(x @ lin0_w.T + lin0_b); thread per (node, out-dim)
__global__ void k_init(const float* __restrict__ x, const float* __restrict__ w,
                       const float* __restrict__ b, float* __restrict__ feat) {
    int idx = blockIdx.x * blockDim.x + threadIdx.x;
    if (idx >= NN * 32) return;
    int n = idx >> 5, o = idx & 31;
    const float* xr = x + n * 11;
    const float* wr = w + o * 11;
    float acc = b[o];
#pragma unroll
    for (int i = 0; i < 11; ++i) acc += xr[i] * wr[i];
    feat[idx] = fmaxf(acc, 0.f);
}

// Rearrange edge-MLP weights into Wre[c][i] ([160][32]) so that k_y's weight
// access is wave-uniform (scalar loads). c = f*32+o for f<4; c = 128+o for bias.
__global__ void k_prep(const float* __restrict__ nnw, const float* __restrict__ nnb,
                       float* __restrict__ Wre) {
    int idx = blockIdx.x * blockDim.x + threadIdx.x;
    if (idx >= 160 * 32) return;
    int c = idx >> 5, i = idx & 31;
    float v;
    if (c < 128) v = nnw[((i << 5) + (c & 31)) * 4 + (c >> 5)];
    else         v = nnb[(i << 5) + (c - 128)];
    Wre[idx] = v;
}

// Per-node message table (GEMM feat[N,32] @ Wre.T -> y[N,160]).
// Lane-per-node: feat row in 32 VGPRs, weights via SGPR (uniform index),
// inner loop is pure v_fma_f32.
__global__ __launch_bounds__(256) void k_y(const float* __restrict__ feat,
                                           const float* __restrict__ Wre,
                                           float* __restrict__ y) {
    int n = blockIdx.x * 256 + threadIdx.x;
    if (n >= NN) return;
    float fr[32];
    const float4* f4 = (const float4*)(feat + (long)n * 32);
#pragma unroll
    for (int q = 0; q < 8; ++q) {
        float4 v = f4[q];
        fr[4 * q + 0] = v.x; fr[4 * q + 1] = v.y;
        fr[4 * q + 2] = v.z; fr[4 * q + 3] = v.w;
    }
    float* yr = y + (long)n * 160;
#pragma unroll 4
    for (int c = 0; c < 160; ++c) {
        const float* w = Wre + c * 32;   // uniform address -> s_load
        float acc = 0.f;
#pragma unroll
        for (int i = 0; i < 32; ++i) acc += fr[i] * w[i];
        yr[c] = acc;
    }
}

// Edge pass: msg[e,o] = y_b[src,o] + sum_f ea[e,f]*y_f[src,o]; scatter-add to aggr[dst]
__global__ void k_edge(const float* __restrict__ y, const float* __restrict__ ea,
                       const int* __restrict__ ei, float* __restrict__ aggr) {
    int idx = blockIdx.x * blockDim.x + threadIdx.x;
    if (idx >= EE * 32) return;
    int e = idx >> 5, o = idx & 31;
    int s = ei[e];
    int d = ei[EE + e];
    const float* yr = y + (long)s * 160;
    float a0 = ea[e * 4 + 0], a1 = ea[e * 4 + 1], a2 = ea[e * 4 + 2], a3 = ea[e * 4 + 3];
    float msg = yr[128 + o] + a0 * yr[o] + a1 * yr[32 + o] + a2 * yr[64 + o] + a3 * yr[96 + o];
    atomicAdd(aggr + (long)d * 32 + o, msg);
}

// Node update: m = relu(aggr + feat@root_w + conv_b); feat = GRU(m, feat)
__global__ __launch_bounds__(256) void k_update(
    const float* __restrict__ aggr, const float* __restrict__ rootw,
    const float* __restrict__ convb, const float* __restrict__ wi,
    const float* __restrict__ wh, const float* __restrict__ bi,
    const float* __restrict__ bh, float* __restrict__ feat) {
    __shared__ float fs[8][32];
    __shared__ float ms[8][32];
    int t = threadIdx.x;
    int l = t >> 5, o = t & 31;
    int n = blockIdx.x * 8 + l;
    bool valid = (n < NN);
    float f = valid ? feat[n * 32 + o] : 0.f;
    fs[l][o] = f;
    __syncthreads();
    float acc = 0.f;
    if (valid) {
        acc = aggr[n * 32 + o] + convb[o];
#pragma unroll
        for (int i = 0; i < 32; ++i) acc += fs[l][i] * rootw[i * 32 + o];
    }
    float m = fmaxf(acc, 0.f);
    ms[l][o] = m;
    __syncthreads();
    if (!valid) return;
    float gir = bi[o], giz = bi[32 + o], gin = bi[64 + o];
    float ghr = bh[o], ghz = bh[32 + o], ghn = bh[64 + o];
#pragma unroll
    for (int k = 0; k < 32; ++k) {
        float mk = ms[l][k], hk = fs[l][k];
        gir += mk * wi[o * 32 + k];
        giz += mk * wi[(32 + o) * 32 + k];
        gin += mk * wi[(64 + o) * 32 + k];
        ghr += hk * wh[o * 32 + k];
        ghz += hk * wh[(32 + o) * 32 + k];
        ghn += hk * wh[(64 + o) * 32 + k];
    }
    float r = 1.f / (1.f + __expf(-(gir + ghr)));
    float z = 1.f / (1.f + __expf(-(giz + ghz)));
    float nt = tanhf(gin + r * ghn);
    feat[n * 32 + o] = (1.f - z) * nt + z * f;
}

// Mean-pool per graph via atomics
__global__ void k_pool(const float* __restrict__ feat, const int* __restrict__ batch,
                       float* __restrict__ pooled, float* __restrict__ cnt) {
    int idx = blockIdx.x * blockDim.x + threadIdx.x;
    if (idx >= NN * 32) return;
    int n = idx >> 5, o = idx & 31;
    int g = batch[n];
    atomicAdd(pooled + (long)g * 32 + o, feat[idx]);
    if (o == 0) atomicAdd(cnt + g, 1.f);
}

// logits = (pooled/cnt) @ lin1_w.T + lin1_b; log_softmax over 2 classes
__global__ void k_final(const float* __restrict__ pooled, const float* __restrict__ cnt,
                        const float* __restrict__ w, const float* __restrict__ b,
                        float* __restrict__ out) {
    int g = blockIdx.x * blockDim.x + threadIdx.x;
    if (g >= GG) return;
    float inv = 1.f / fmaxf(cnt[g], 1.f);
    float l0 = b[0], l1 = b[1];
    const float* pr = pooled + g * 32;
#pragma unroll
    for (int k = 0; k < 32; ++k) {
        float p = pr[k] * inv;
        l0 += p * w[k];
        l1 += p * w[32 + k];
    }
    float mx = fmaxf(l0, l1);
    float lse = mx + logf(__expf(l0 - mx) + __expf(l1 - mx));
    out[g * 2 + 0] = l0 - lse;
    out[g * 2 + 1] = l1 - lse;
}

extern "C" void kernel_launch(void* const* d_in, const int* in_sizes, int n_in,
                              void* d_out, int out_size, void* d_ws, size_t ws_size,
                              hipStream_t stream) {
    const float* x        = (const float*)d_in[0];
    const float* edge_attr= (const float*)d_in[1];
    const float* lin0_w   = (const float*)d_in[2];
    const float* lin0_b   = (const float*)d_in[3];
    const float* nn_w     = (const float*)d_in[4];
    const float* nn_b     = (const float*)d_in[5];
    const float* root_w   = (const float*)d_in[6];
    const float* conv_b   = (const float*)d_in[7];
    const float* gru_wi   = (const float*)d_in[8];
    const float* gru_wh   = (const float*)d_in[9];
    const float* gru_bi   = (const float*)d_in[10];
    const float* gru_bh   = (const float*)d_in[11];
    const float* lin1_w   = (const float*)d_in[12];
    const float* lin1_b   = (const float*)d_in[13];
    const int*   edge_idx = (const int*)d_in[14];
    const int*   batch    = (const int*)d_in[15];
    float* out = (float*)d_out;

    float* ws     = (float*)d_ws;
    float* feat   = ws;                       // N*32   = 1,600,000 f
    float* y      = feat + (long)NN * 32;     // N*160  = 8,000,000 f
    float* aggr   = y + (long)NN * 160;       // N*32   = 1,600,000 f
    float* pooled = aggr + (long)NN * 32;     // G*32   =    65,536 f
    float* cnt    = pooled + (long)GG * 32;   // G      =     2,048 f
    float* Wre    = cnt + GG;                 // 160*32 =     5,120 f
    // total ~45.2 MB

    hipMemsetAsync(pooled, 0, ((long)GG * 32 + GG) * sizeof(float), stream);

    k_prep<<<(160 * 32 + 255) / 256, 256, 0, stream>>>(nn_w, nn_b, Wre);
    k_init<<<(NN * 32 + 255) / 256, 256, 0, stream>>>(x, lin0_w, lin0_b, feat);

    for (int it = 0; it < 3; ++it) {
        k_y<<<(NN + 255) / 256, 256, 0, stream>>>(feat, Wre, y);
        hipMemsetAsync(aggr, 0, (long)NN * 32 * sizeof(float), stream);
        k_edge<<<(EE * 32 + 255) / 256, 256, 0, stream>>>(y, edge_attr, edge_idx, aggr);
        k_update<<<(NN + 7) / 8, 256, 0, stream>>>(aggr, root_w, conv_b, gru_wi, gru_wh,
                                                   gru_bi, gru_bh, feat);
    }

    k_pool<<<(NN * 32 + 255) / 256, 256, 0, stream>>>(feat, batch, pooled, cnt);
    k_final<<<(GG + 255) / 256, 256, 0, stream>>>(pooled, cnt, lin1_w, lin1_b, out);
}

// Round 3
// 598.065 us; speedup vs baseline: 2.0540x; 1.3678x over previous
//
#include <hip/hip_runtime.h>
#include <hip/hip_bf16.h>

// Problem constants (from reference)
#define NN 50000
#define EE 100000
#define GG 2048
// D = 32 hidden, F_NODE = 11, F_EDGE = 4

// feat = relu(x @ lin0_w.T + lin0_b); thread per (node, out-dim)
__global__ void k_init(const float* __restrict__ x, const float* __restrict__ w,
                       const float* __restrict__ b, float* __restrict__ feat) {
    int idx = blockIdx.x * blockDim.x + threadIdx.x;
    if (idx >= NN * 32) return;
    int n = idx >> 5, o = idx & 31;
    const float* xr = x + n * 11;
    const float* wr = w + o * 11;
    float acc = b[o];
#pragma unroll
    for (int i = 0; i < 11; ++i) acc += xr[i] * wr[i];
    feat[idx] = fmaxf(acc, 0.f);
}

// Rearrange edge-MLP weights into Wre[c][i] ([160][32]) so that k_y's weight
// access is wave-uniform (scalar loads). c = f*32+o for f<4; c = 128+o for bias.
__global__ void k_prep(const float* __restrict__ nnw, const float* __restrict__ nnb,
                       float* __restrict__ Wre) {
    int idx = blockIdx.x * blockDim.x + threadIdx.x;
    if (idx >= 160 * 32) return;
    int c = idx >> 5, i = idx & 31;
    float v;
    if (c < 128) v = nnw[((i << 5) + (c & 31)) * 4 + (c >> 5)];
    else         v = nnb[(i << 5) + (c - 128)];
    Wre[idx] = v;
}

// Per-node message table (GEMM feat[N,32] @ Wre.T -> y[N,160]).
// Lane-per-node: feat row in 32 VGPRs, weights via SGPR (uniform index),
// inner loop is pure v_fma_f32.
__global__ __launch_bounds__(256) void k_y(const float* __restrict__ feat,
                                           const float* __restrict__ Wre,
                                           float* __restrict__ y) {
    int n = blockIdx.x * 256 + threadIdx.x;
    if (n >= NN) return;
    float fr[32];
    const float4* f4 = (const float4*)(feat + (long)n * 32);
#pragma unroll
    for (int q = 0; q < 8; ++q) {
        float4 v = f4[q];
        fr[4 * q + 0] = v.x; fr[4 * q + 1] = v.y;
        fr[4 * q + 2] = v.z; fr[4 * q + 3] = v.w;
    }
    float* yr = y + (long)n * 160;
#pragma unroll 4
    for (int c = 0; c < 160; ++c) {
        const float* w = Wre + c * 32;   // uniform address -> s_load
        float acc = 0.f;
#pragma unroll
        for (int i = 0; i < 32; ++i) acc += fr[i] * w[i];
        yr[c] = acc;
    }
}

// Edge pass: msg[e,o] = y_b[src,o] + sum_f ea[e,f]*y_f[src,o]; scatter-add to aggr[dst]
__global__ void k_edge(const float* __restrict__ y, const float* __restrict__ ea,
                       const int* __restrict__ ei, float* __restrict__ aggr) {
    int idx = blockIdx.x * blockDim.x + threadIdx.x;
    if (idx >= EE * 32) return;
    int e = idx >> 5, o = idx & 31;
    int s = ei[e];
    int d = ei[EE + e];
    const float* yr = y + (long)s * 160;
    float a0 = ea[e * 4 + 0], a1 = ea[e * 4 + 1], a2 = ea[e * 4 + 2], a3 = ea[e * 4 + 3];
    float msg = yr[128 + o] + a0 * yr[o] + a1 * yr[32 + o] + a2 * yr[64 + o] + a3 * yr[96 + o];
    atomicAdd(aggr + (long)d * 32 + o, msg);
}

// Node update: m = relu(aggr + feat@root_w + conv_b); feat = GRU(m, feat)
// Lane-per-node: f[32], m[32] in VGPRs; all weight accesses wave-uniform
// (loop-counter indices only) -> s_load + v_fma with SGPR operand.
__global__ __launch_bounds__(256) void k_update(
    const float* __restrict__ aggr, const float* __restrict__ rootw,
    const float* __restrict__ convb, const float* __restrict__ wi,
    const float* __restrict__ wh, const float* __restrict__ bi,
    const float* __restrict__ bh, float* __restrict__ feat) {
    int n = blockIdx.x * 256 + threadIdx.x;
    if (n >= NN) return;
    float f[32], m[32];
    const float4* f4 = (const float4*)(feat + (long)n * 32);
    const float4* a4 = (const float4*)(aggr + (long)n * 32);
#pragma unroll
    for (int q = 0; q < 8; ++q) {
        float4 v = f4[q];
        f[4 * q + 0] = v.x; f[4 * q + 1] = v.y;
        f[4 * q + 2] = v.z; f[4 * q + 3] = v.w;
    }
#pragma unroll
    for (int q = 0; q < 8; ++q) {
        float4 v = a4[q];
        m[4 * q + 0] = v.x + convb[4 * q + 0];
        m[4 * q + 1] = v.y + convb[4 * q + 1];
        m[4 * q + 2] = v.z + convb[4 * q + 2];
        m[4 * q + 3] = v.w + convb[4 * q + 3];
    }
    // m[o] += sum_i f[i] * rootw[i*32+o]; i-outer so each i reads one
    // contiguous 128B weight row (s_load_dwordx16 x2)
#pragma unroll 2
    for (int i = 0; i < 32; ++i) {
        float fi = f[i];
        const float* wr = rootw + i * 32;
#pragma unroll
        for (int o = 0; o < 32; ++o) m[o] += fi * wr[o];
    }
#pragma unroll
    for (int o = 0; o < 32; ++o) m[o] = fmaxf(m[o], 0.f);

    float* fout = feat + (long)n * 32;
#pragma unroll 2
    for (int o = 0; o < 32; ++o) {
        float gir = bi[o], giz = bi[32 + o], gin = bi[64 + o];
        float ghr = bh[o], ghz = bh[32 + o], ghn = bh[64 + o];
        const float* wir = wi + o * 32;
        const float* wiz = wi + (32 + o) * 32;
        const float* win = wi + (64 + o) * 32;
        const float* whr = wh + o * 32;
        const float* whz = wh + (32 + o) * 32;
        const float* whn = wh + (64 + o) * 32;
#pragma unroll
        for (int k = 0; k < 32; ++k) {
            float mk = m[k], hk = f[k];
            gir += mk * wir[k];
            giz += mk * wiz[k];
            gin += mk * win[k];
            ghr += hk * whr[k];
            ghz += hk * whz[k];
            ghn += hk * whn[k];
        }
        float r = 1.f / (1.f + __expf(-(gir + ghr)));
        float z = 1.f / (1.f + __expf(-(giz + ghz)));
        float nt = tanhf(gin + r * ghn);
        fout[o] = (1.f - z) * nt + z * f[o];
    }
}

// Mean-pool per graph via atomics
__global__ void k_pool(const float* __restrict__ feat, const int* __restrict__ batch,
                       float* __restrict__ pooled, float* __restrict__ cnt) {
    int idx = blockIdx.x * blockDim.x + threadIdx.x;
    if (idx >= NN * 32) return;
    int n = idx >> 5, o = idx & 31;
    int g = batch[n];
    atomicAdd(pooled + (long)g * 32 + o, feat[idx]);
    if (o == 0) atomicAdd(cnt + g, 1.f);
}

// logits = (pooled/cnt) @ lin1_w.T + lin1_b; log_softmax over 2 classes
__global__ void k_final(const float* __restrict__ pooled, const float* __restrict__ cnt,
                        const float* __restrict__ w, const float* __restrict__ b,
                        float* __restrict__ out) {
    int g = blockIdx.x * blockDim.x + threadIdx.x;
    if (g >= GG) return;
    float inv = 1.f / fmaxf(cnt[g], 1.f);
    float l0 = b[0], l1 = b[1];
    const float* pr = pooled + g * 32;
#pragma unroll
    for (int k = 0; k < 32; ++k) {
        float p = pr[k] * inv;
        l0 += p * w[k];
        l1 += p * w[32 + k];
    }
    float mx = fmaxf(l0, l1);
    float lse = mx + logf(__expf(l0 - mx) + __expf(l1 - mx));
    out[g * 2 + 0] = l0 - lse;
    out[g * 2 + 1] = l1 - lse;
}

extern "C" void kernel_launch(void* const* d_in, const int* in_sizes, int n_in,
                              void* d_out, int out_size, void* d_ws, size_t ws_size,
                              hipStream_t stream) {
    const float* x        = (const float*)d_in[0];
    const float* edge_attr= (const float*)d_in[1];
    const float* lin0_w   = (const float*)d_in[2];
    const float* lin0_b   = (const float*)d_in[3];
    const float* nn_w     = (const float*)d_in[4];
    const float* nn_b     = (const float*)d_in[5];
    const float* root_w   = (const float*)d_in[6];
    const float* conv_b   = (const float*)d_in[7];
    const float* gru_wi   = (const float*)d_in[8];
    const float* gru_wh   = (const float*)d_in[9];
    const float* gru_bi   = (const float*)d_in[10];
    const float* gru_bh   = (const float*)d_in[11];
    const float* lin1_w   = (const float*)d_in[12];
    const float* lin1_b   = (const float*)d_in[13];
    const int*   edge_idx = (const int*)d_in[14];
    const int*   batch    = (const int*)d_in[15];
    float* out = (float*)d_out;

    float* ws     = (float*)d_ws;
    float* feat   = ws;                       // N*32   = 1,600,000 f
    float* y      = feat + (long)NN * 32;     // N*160  = 8,000,000 f
    float* aggr   = y + (long)NN * 160;       // N*32   = 1,600,000 f
    float* pooled = aggr + (long)NN * 32;     // G*32   =    65,536 f
    float* cnt    = pooled + (long)GG * 32;   // G      =     2,048 f
    float* Wre    = cnt + GG;                 // 160*32 =     5,120 f
    // total ~45.2 MB

    hipMemsetAsync(pooled, 0, ((long)GG * 32 + GG) * sizeof(float), stream);

    k_prep<<<(160 * 32 + 255) / 256, 256, 0, stream>>>(nn_w, nn_b, Wre);
    k_init<<<(NN * 32 + 255) / 256, 256, 0, stream>>>(x, lin0_w, lin0_b, feat);

    for (int it = 0; it < 3; ++it) {
        k_y<<<(NN + 255) / 256, 256, 0, stream>>>(feat, Wre, y);
        hipMemsetAsync(aggr, 0, (long)NN * 32 * sizeof(float), stream);
        k_edge<<<(EE * 32 + 255) / 256, 256, 0, stream>>>(y, edge_attr, edge_idx, aggr);
        k_update<<<(NN + 255) / 256, 256, 0, stream>>>(aggr, root_w, conv_b, gru_wi, gru_wh,
                                                       gru_bi, gru_bh, feat);
    }

    k_pool<<<(NN * 32 + 255) / 256, 256, 0, stream>>>(feat, batch, pooled, cnt);
    k_final<<<(GG + 255) / 256, 256, 0, stream>>>(pooled, cnt, lin1_w, lin1_b, out);
}

// Round 4
// 388.203 us; speedup vs baseline: 3.1644x; 1.5406x over previous
//
#include <hip/hip_runtime.h>
#include <hip/hip_bf16.h>

// Problem constants (from reference)
#define NN 50000
#define EE 100000
#define GG 2048
// D = 32 hidden, F_NODE = 11, F_EDGE = 4

// feat = relu(x @ lin0_w.T + lin0_b); thread per (node, out-dim)
__global__ void k_init(const float* __restrict__ x, const float* __restrict__ w,
                       const float* __restrict__ b, float* __restrict__ feat) {
    int idx = blockIdx.x * blockDim.x + threadIdx.x;
    if (idx >= NN * 32) return;
    int n = idx >> 5, o = idx & 31;
    const float* xr = x + n * 11;
    const float* wr = w + o * 11;
    float acc = b[o];
#pragma unroll
    for (int i = 0; i < 11; ++i) acc += xr[i] * wr[i];
    feat[idx] = fmaxf(acc, 0.f);
}

// Rearrange edge-MLP weights into Wre[c][i] ([160][32]) so that k_y's weight
// access is wave-uniform (scalar loads). c = f*32+o for f<4; c = 128+o for bias.
__global__ void k_prep(const float* __restrict__ nnw, const float* __restrict__ nnb,
                       float* __restrict__ Wre) {
    int idx = blockIdx.x * blockDim.x + threadIdx.x;
    if (idx >= 160 * 32) return;
    int c = idx >> 5, i = idx & 31;
    float v;
    if (c < 128) v = nnw[((i << 5) + (c & 31)) * 4 + (c >> 5)];
    else         v = nnb[(i << 5) + (c - 128)];
    Wre[idx] = v;
}

// Per-node message table (GEMM feat[N,32] @ Wre.T -> y[N,160]).
// Lane = node (weights wave-uniform -> s_load); wave computes a 20-col slice
// of the 160-wide output row. Grid (782, 2) x 4 waves => 6256 waves.
__global__ __launch_bounds__(256) void k_y(const float* __restrict__ feat,
                                           const float* __restrict__ Wre,
                                           float* __restrict__ y) {
    int lane = threadIdx.x & 63;
    int wv = __builtin_amdgcn_readfirstlane(threadIdx.x >> 6);
    int n = blockIdx.x * 64 + lane;
    if (n >= NN) return;
    int c0 = blockIdx.y * 80 + wv * 20;
    float fr[32];
    const float4* f4 = (const float4*)(feat + (long)n * 32);
#pragma unroll
    for (int q = 0; q < 8; ++q) {
        float4 v = f4[q];
        fr[4 * q + 0] = v.x; fr[4 * q + 1] = v.y;
        fr[4 * q + 2] = v.z; fr[4 * q + 3] = v.w;
    }
    float acc[20];
#pragma unroll
    for (int cc = 0; cc < 20; ++cc) {
        const float* w = Wre + (c0 + cc) * 32;   // uniform address -> s_load
        float a = 0.f;
#pragma unroll
        for (int i = 0; i < 32; ++i) a += fr[i] * w[i];
        acc[cc] = a;
    }
    float* yr = y + (long)n * 160 + c0;          // c0 % 4 == 0 -> 16B aligned
#pragma unroll
    for (int q = 0; q < 5; ++q) {
        float4 v = make_float4(acc[4 * q + 0], acc[4 * q + 1],
                               acc[4 * q + 2], acc[4 * q + 3]);
        ((float4*)yr)[q] = v;
    }
}

// Edge pass: msg[e,o] = y_b[src,o] + sum_f ea[e,f]*y_f[src,o]; scatter-add to aggr[dst]
__global__ void k_edge(const float* __restrict__ y, const float* __restrict__ ea,
                       const int* __restrict__ ei, float* __restrict__ aggr) {
    int idx = blockIdx.x * blockDim.x + threadIdx.x;
    if (idx >= EE * 32) return;
    int e = idx >> 5, o = idx & 31;
    int s = ei[e];
    int d = ei[EE + e];
    const float* yr = y + (long)s * 160;
    float a0 = ea[e * 4 + 0], a1 = ea[e * 4 + 1], a2 = ea[e * 4 + 2], a3 = ea[e * 4 + 3];
    float msg = yr[128 + o] + a0 * yr[o] + a1 * yr[32 + o] + a2 * yr[64 + o] + a3 * yr[96 + o];
    atomicAdd(aggr + (long)d * 32 + o, msg);
}

// Node update: m = relu(aggr + feat@root_w + conv_b); feat = GRU(m, feat)
// Lane = node; each of 4 waves computes full m[32] (redundant, no LDS) then
// an 8-output GRU slice. All weight indices wave-uniform -> s_load.
// __syncthreads separates the feat reads (all waves) from sliced feat writes.
__global__ __launch_bounds__(256) void k_update(
    const float* __restrict__ aggr, const float* __restrict__ rootw,
    const float* __restrict__ convb, const float* __restrict__ wi,
    const float* __restrict__ wh, const float* __restrict__ bi,
    const float* __restrict__ bh, float* __restrict__ feat) {
    int lane = threadIdx.x & 63;
    int wv = __builtin_amdgcn_readfirstlane(threadIdx.x >> 6);
    int n = blockIdx.x * 64 + lane;
    bool valid = (n < NN);
    float f[32], m[32];
    if (valid) {
        const float4* f4 = (const float4*)(feat + (long)n * 32);
        const float4* a4 = (const float4*)(aggr + (long)n * 32);
#pragma unroll
        for (int q = 0; q < 8; ++q) {
            float4 v = f4[q];
            f[4 * q + 0] = v.x; f[4 * q + 1] = v.y;
            f[4 * q + 2] = v.z; f[4 * q + 3] = v.w;
        }
#pragma unroll
        for (int q = 0; q < 8; ++q) {
            float4 v = a4[q];
            m[4 * q + 0] = v.x + convb[4 * q + 0];
            m[4 * q + 1] = v.y + convb[4 * q + 1];
            m[4 * q + 2] = v.z + convb[4 * q + 2];
            m[4 * q + 3] = v.w + convb[4 * q + 3];
        }
    } else {
#pragma unroll
        for (int q = 0; q < 32; ++q) { f[q] = 0.f; m[q] = 0.f; }
    }
    // all feat reads done before any feat writes
    __syncthreads();

    // m[o] += sum_i f[i] * rootw[i*32+o]; uniform contiguous weight rows
#pragma unroll 2
    for (int i = 0; i < 32; ++i) {
        float fi = f[i];
        const float* wr = rootw + i * 32;
#pragma unroll
        for (int o = 0; o < 32; ++o) m[o] += fi * wr[o];
    }
#pragma unroll
    for (int o = 0; o < 32; ++o) m[o] = fmaxf(m[o], 0.f);

    int o0 = wv * 8;
    float res[8];
#pragma unroll 2
    for (int j = 0; j < 8; ++j) {
        int o = o0 + j;
        float gir = bi[o], giz = bi[32 + o], gin = bi[64 + o];
        float ghr = bh[o], ghz = bh[32 + o], ghn = bh[64 + o];
        const float* wir = wi + o * 32;
        const float* wiz = wi + (32 + o) * 32;
        const float* win = wi + (64 + o) * 32;
        const float* whr = wh + o * 32;
        const float* whz = wh + (32 + o) * 32;
        const float* whn = wh + (64 + o) * 32;
#pragma unroll
        for (int k = 0; k < 32; ++k) {
            float mk = m[k], hk = f[k];
            gir += mk * wir[k];
            giz += mk * wiz[k];
            gin += mk * win[k];
            ghr += hk * whr[k];
            ghz += hk * whz[k];
            ghn += hk * whn[k];
        }
        float r = 1.f / (1.f + __expf(-(gir + ghr)));
        float z = 1.f / (1.f + __expf(-(giz + ghz)));
        float nt = tanhf(gin + r * ghn);
        res[j] = (1.f - z) * nt + z * f[o];
    }
    if (valid) {
        float* fo = feat + (long)n * 32 + o0;
        ((float4*)fo)[0] = make_float4(res[0], res[1], res[2], res[3]);
        ((float4*)fo)[1] = make_float4(res[4], res[5], res[6], res[7]);
    }
}

// Mean-pool per graph via atomics
__global__ void k_pool(const float* __restrict__ feat, const int* __restrict__ batch,
                       float* __restrict__ pooled, float* __restrict__ cnt) {
    int idx = blockIdx.x * blockDim.x + threadIdx.x;
    if (idx >= NN * 32) return;
    int n = idx >> 5, o = idx & 31;
    int g = batch[n];
    atomicAdd(pooled + (long)g * 32 + o, feat[idx]);
    if (o == 0) atomicAdd(cnt + g, 1.f);
}

// logits = (pooled/cnt) @ lin1_w.T + lin1_b; log_softmax over 2 classes
__global__ void k_final(const float* __restrict__ pooled, const float* __restrict__ cnt,
                        const float* __restrict__ w, const float* __restrict__ b,
                        float* __restrict__ out) {
    int g = blockIdx.x * blockDim.x + threadIdx.x;
    if (g >= GG) return;
    float inv = 1.f / fmaxf(cnt[g], 1.f);
    float l0 = b[0], l1 = b[1];
    const float* pr = pooled + g * 32;
#pragma unroll
    for (int k = 0; k < 32; ++k) {
        float p = pr[k] * inv;
        l0 += p * w[k];
        l1 += p * w[32 + k];
    }
    float mx = fmaxf(l0, l1);
    float lse = mx + logf(__expf(l0 - mx) + __expf(l1 - mx));
    out[g * 2 + 0] = l0 - lse;
    out[g * 2 + 1] = l1 - lse;
}

extern "C" void kernel_launch(void* const* d_in, const int* in_sizes, int n_in,
                              void* d_out, int out_size, void* d_ws, size_t ws_size,
                              hipStream_t stream) {
    const float* x        = (const float*)d_in[0];
    const float* edge_attr= (const float*)d_in[1];
    const float* lin0_w   = (const float*)d_in[2];
    const float* lin0_b   = (const float*)d_in[3];
    const float* nn_w     = (const float*)d_in[4];
    const float* nn_b     = (const float*)d_in[5];
    const float* root_w   = (const float*)d_in[6];
    const float* conv_b   = (const float*)d_in[7];
    const float* gru_wi   = (const float*)d_in[8];
    const float* gru_wh   = (const float*)d_in[9];
    const float* gru_bi   = (const float*)d_in[10];
    const float* gru_bh   = (const float*)d_in[11];
    const float* lin1_w   = (const float*)d_in[12];
    const float* lin1_b   = (const float*)d_in[13];
    const int*   edge_idx = (const int*)d_in[14];
    const int*   batch    = (const int*)d_in[15];
    float* out = (float*)d_out;

    float* ws     = (float*)d_ws;
    float* feat   = ws;                       // N*32   = 1,600,000 f
    float* y      = feat + (long)NN * 32;     // N*160  = 8,000,000 f
    float* aggr   = y + (long)NN * 160;       // N*32   = 1,600,000 f
    float* pooled = aggr + (long)NN * 32;     // G*32   =    65,536 f
    float* cnt    = pooled + (long)GG * 32;   // G      =     2,048 f
    float* Wre    = cnt + GG;                 // 160*32 =     5,120 f
    // total ~45.2 MB

    hipMemsetAsync(pooled, 0, ((long)GG * 32 + GG) * sizeof(float), stream);

    k_prep<<<(160 * 32 + 255) / 256, 256, 0, stream>>>(nn_w, nn_b, Wre);
    k_init<<<(NN * 32 + 255) / 256, 256, 0, stream>>>(x, lin0_w, lin0_b, feat);

    dim3 gy((NN + 63) / 64, 2);
    for (int it = 0; it < 3; ++it) {
        k_y<<<gy, 256, 0, stream>>>(feat, Wre, y);
        hipMemsetAsync(aggr, 0, (long)NN * 32 * sizeof(float), stream);
        k_edge<<<(EE * 32 + 255) / 256, 256, 0, stream>>>(y, edge_attr, edge_idx, aggr);
        k_update<<<(NN + 63) / 64, 256, 0, stream>>>(aggr, root_w, conv_b, gru_wi, gru_wh,
                                                     gru_bi, gru_bh, feat);
    }

    k_pool<<<(NN * 32 + 255) / 256, 256, 0, stream>>>(feat, batch, pooled, cnt);
    k_final<<<(GG + 255) / 256, 256, 0, stream>>>(pooled, cnt, lin1_w, lin1_b, out);
}